// Round 5
// baseline (14.407 us; speedup 1.0000x reference)
//
#include <hip/hip_runtime.h>

// VocabParallelEmbeddingWithTopping: per-token routed embedding gather.
// out[t, :] = (wi[t] == -1 ? base_weight[id[t], :] : delta_weights[wi[t], id[t], :])
//
// N = 8192 tokens, D = 1024 fp32 (4 KiB rows).
// One wave handles 8 tokens in two half-batches of 4:
//   [int4 index loads for all 8] -> load 16 f32x4 -> store 16 -> load 16 -> store 16
// Index overhead halved vs R4; MLP stays 16 loads deep; live regs capped at
// ~16 f32x4. Grid = 8192/32 = 256 blocks x 256 threads (1024 waves).

static constexpr int kVocab    = 32000;
static constexpr int kEmbedDim = 1024;

typedef float f32x4 __attribute__((ext_vector_type(4)));
typedef int   i32x4 __attribute__((ext_vector_type(4)));

__global__ __launch_bounds__(256) void routed_embed_kernel(
    const int* __restrict__ input_ids,
    const int* __restrict__ weight_indices,
    const float* __restrict__ base_weight,
    const float* __restrict__ delta_weights,
    float* __restrict__ out) {
    const int wave = threadIdx.x >> 6;
    const int lane = threadIdx.x & 63;
    const int t0   = (blockIdx.x * 4 + wave) * 8;  // first of this wave's 8 tokens

    // 8 ids + 8 route indices via two int4 broadcast loads each.
    const i32x4 ids_lo = *reinterpret_cast<const i32x4*>(input_ids + t0);
    const i32x4 ids_hi = *reinterpret_cast<const i32x4*>(input_ids + t0 + 4);
    const i32x4 wis_lo = *reinterpret_cast<const i32x4*>(weight_indices + t0);
    const i32x4 wis_hi = *reinterpret_cast<const i32x4*>(weight_indices + t0 + 4);

    const f32x4* __restrict__ s4[8];
#pragma unroll
    for (int k = 0; k < 4; ++k) {
        {
            const int id = ids_lo[k], wi = wis_lo[k];
            s4[k] = reinterpret_cast<const f32x4*>(
                (wi < 0) ? base_weight + (size_t)id * kEmbedDim
                         : delta_weights + ((size_t)wi * kVocab + (size_t)id) * kEmbedDim);
        }
        {
            const int id = ids_hi[k], wi = wis_hi[k];
            s4[4 + k] = reinterpret_cast<const f32x4*>(
                (wi < 0) ? base_weight + (size_t)id * kEmbedDim
                         : delta_weights + ((size_t)wi * kVocab + (size_t)id) * kEmbedDim);
        }
    }

    // Two half-batches: 16 loads in flight, then 16 stores.
#pragma unroll
    for (int h = 0; h < 2; ++h) {
        f32x4 v[4][4];
#pragma unroll
        for (int k = 0; k < 4; ++k)
#pragma unroll
            for (int j = 0; j < 4; ++j)
                v[k][j] = s4[h * 4 + k][lane + 64 * j];

#pragma unroll
        for (int k = 0; k < 4; ++k) {
            f32x4* __restrict__ o4 = reinterpret_cast<f32x4*>(
                out + (size_t)(t0 + h * 4 + k) * kEmbedDim);
#pragma unroll
            for (int j = 0; j < 4; ++j)
                __builtin_nontemporal_store(v[k][j], &o4[lane + 64 * j]);
        }
    }
}

extern "C" void kernel_launch(void* const* d_in, const int* in_sizes, int n_in,
                              void* d_out, int out_size, void* d_ws, size_t ws_size,
                              hipStream_t stream) {
    const int*   input_ids      = (const int*)d_in[0];
    const int*   weight_indices = (const int*)d_in[1];
    const float* base_weight    = (const float*)d_in[2];
    const float* delta_weights  = (const float*)d_in[3];
    float*       out            = (float*)d_out;

    const int num_tokens = in_sizes[0];  // 8192, divisible by 32
    const int grid       = num_tokens / 32;

    routed_embed_kernel<<<grid, 256, 0, stream>>>(
        input_ids, weight_indices, base_weight, delta_weights, out);
}